// Round 16
// baseline (45.766 us; speedup 1.0000x reference)
//
#include <hip/hip_runtime.h>

#define B_ 32
#define L_ 512
#define D_ 1024
#define S_ 256
#define E_ 64
#define POS_ 17
#define LWS 2065   // 2*D + POS
#define M_ (B_*S_) // 8192

typedef __attribute__((ext_vector_type(8))) short short8v;
typedef __attribute__((ext_vector_type(4))) float f32x4;
typedef __attribute__((ext_vector_type(16))) float f32x16;
typedef __attribute__((ext_vector_type(4))) unsigned short us4;

__device__ __forceinline__ unsigned short f2bf(float x) {
  union { float f; unsigned u; } v; v.f = x;
  unsigned r = v.u + 0x7FFFu + ((v.u >> 16) & 1u);
  return (unsigned short)(r >> 16);
}
__device__ __forceinline__ float bf2f(unsigned short b) {
  union { unsigned u; float f; } v; v.u = ((unsigned)b) << 16;
  return v.f;
}
// async global->LDS, 16B per lane. LDS dest must be linear (base + lane*16).
__device__ __forceinline__ void async16(void* lds, const void* g) {
  __builtin_amdgcn_global_load_lds(
      (const __attribute__((address_space(1))) unsigned int*)(unsigned long long)g,
      (__attribute__((address_space(3))) unsigned int*)(unsigned int)(unsigned long long)lds,
      16, 0, 0);
}

#define VMCNT4 asm volatile("s_waitcnt vmcnt(4)" ::: "memory")
#define VMCNT0 asm volatile("s_waitcnt vmcnt(0)" ::: "memory")
#define BARRIER __builtin_amdgcn_s_barrier()

// ---------------------------------------------------------------------------
// prep_all: one kernel, three roles by blockIdx range. Gather phases are
// ONE WAVE PER ROW, barrier-free (in-wave shfl reductions only).
//   [0, 2048)     : sent rows, 4/block (XCD-aligned: bid&7 owns rows
//                   [xcd*1024, +1024) to match gemm's XCD m-panels)
//   [2048, 2560)  : event rows, 4/block
//   [2560, 3584)  : W[k][n] f32 -> Wt[n][k] bf16 (32x32 tiles)
// ---------------------------------------------------------------------------
__global__ __launch_bounds__(256) void prep_all(
    const float* __restrict__ emb, const float* __restrict__ W,
    const float* __restrict__ lin_w, const float* __restrict__ lin_b,
    const int* __restrict__ idx_s, const int* __restrict__ idx_e,
    const int* __restrict__ pos_tag,
    unsigned short* __restrict__ sentb, unsigned short* __restrict__ evb,
    unsigned short* __restrict__ Wt,
    float* __restrict__ base, float* __restrict__ ne, float* __restrict__ evw) {
  int bid = blockIdx.x;
  int t = threadIdx.x;

  if (bid >= 2560) {  // ---- W transpose ----
    __shared__ float tile[32][33];
    int tt = bid - 2560;
    int bx = tt & 31, by = tt >> 5;
    int tx = t & 31, ty = t >> 5;  // 32 x 8
#pragma unroll
    for (int i = 0; i < 4; i++)
      tile[ty + i * 8][tx] = W[(size_t)(by * 32 + ty + i * 8) * D_ + bx * 32 + tx];
    __syncthreads();
#pragma unroll
    for (int i = 0; i < 4; i++)
      Wt[(size_t)(bx * 32 + ty + i * 8) * D_ + by * 32 + tx] = f2bf(tile[tx][ty + i * 8]);
    return;
  }

  int lane = t & 63, w = t >> 6;
  bool is_sent = bid < 2048;
  // sent: XCD-aligned bijection row = xcd*1024 + (bid>>3)*4 + w
  int row = is_sent ? (((bid & 7) << 10) | ((bid >> 3) << 2) | w)
                    : (((bid - 2048) << 2) | w);
  int b = is_sent ? (row >> 8) : (row >> 6);
  int idx = is_sent ? idx_s[row] : idx_e[row];
  float msk = idx > 0 ? 1.0f : 0.0f;
  const float* src = emb + ((size_t)b * L_ + (idx > 0 ? idx : 0)) * D_;

  float r0 = 0.f, r1 = 0.f, sq = 0.f;
  const float* lw0 = is_sent ? lin_w : (lin_w + D_);
  const float* lw1 = is_sent ? (lin_w + LWS) : (lin_w + LWS + D_);
  unsigned short* dst = is_sent ? (sentb + (size_t)row * D_)
                                : (evb + (size_t)row * D_);
#pragma unroll
  for (int j = 0; j < 4; j++) {
    int d = j * 256 + lane * 4;
    float4 v = *(const float4*)(src + d);
    v.x *= msk; v.y *= msk; v.z *= msk; v.w *= msk;
    us4 o; o.x = f2bf(v.x); o.y = f2bf(v.y); o.z = f2bf(v.z); o.w = f2bf(v.w);
    *(us4*)&dst[d] = o;
    float4 c0 = *(const float4*)(lw0 + d);              // 16B-aligned
    float4 c1 = *(const float4*)(lw1 + d);              // 4B-aligned (legal)
    r0 += v.x * c0.x + v.y * c0.y + v.z * c0.z + v.w * c0.w;
    r1 += v.x * c1.x + v.y * c1.y + v.z * c1.z + v.w * c1.w;
    if (!is_sent) sq += v.x * v.x + v.y * v.y + v.z * v.z + v.w * v.w;
  }
#pragma unroll
  for (int off = 32; off; off >>= 1) {
    r0 += __shfl_xor(r0, off);
    r1 += __shfl_xor(r1, off);
  }
  if (is_sent) {
    if (lane == 0) {
      int p = pos_tag[row]; if (p < 0) p = POS_ - 1;
      base[(size_t)row * 2 + 0] = r0 + lin_b[0] + lin_w[2 * D_ + p];
      base[(size_t)row * 2 + 1] = r1 + lin_b[1] + lin_w[LWS + 2 * D_ + p];
    }
  } else {
#pragma unroll
    for (int off = 32; off; off >>= 1) sq += __shfl_xor(sq, off);
    if (lane == 0) {
      ne[row] = fmaxf(sqrtf(sq), 1e-8f);
      evw[(size_t)row * 2 + 0] = r0;
      evw[(size_t)row * 2 + 1] = r1;
    }
  }
}

// ---------------------------------------------------------------------------
// gemm: a = sent @ W. 128x128 tile, BK=32 (m97's proven occupancy regime:
// 32 KB LDS total -> 4-5 blocks/CU vs BK=64's 2), double-buffered,
// counted-vmcnt pipeline (4 loads/wave per stage stay in flight).
// R13 counters for the BK=64 variant: MfmaUtil 16%, VALU 9%, HBM 8%,
// Occ 19% -> latency/occupancy-bound; BK=64's 64KB LDS is the m132
// regression regime (2 blocks/CU).
// Bank swizzle for 64B rows: 4 chunks/row can't cover 32 banks, but row
// parity shifts bank base by 16, so chunk ^= (row>>1)&3 makes each
// lane-octet cover all 32 banks. Same involution on stage source and read.
// 32x32x16 MFMA; XCD-chunked (XCD x owns m-rows [x*1024, +1024)).
// NOTE (R9 lesson): never read MFMA operands directly from global inside
// this loop — direct vmem reads share the vmcnt queue with global_load_lds
// and their waits drain the async pipeline (MfmaUtil 37%->13%, measured).
// ---------------------------------------------------------------------------
__device__ __forceinline__ void stage_g(const char* gA, const char* gB,
    unsigned short* bA, unsigned short* bB, int t, int kt) {
  // 128 rows x 4 chunks(16B) per matrix = 512 chunks; 2 per thread each.
#pragma unroll
  for (int i = 0; i < 2; i++) {
    int idx = i * 256 + t;
    int row = idx >> 2;
    int ch = (idx & 3) ^ ((row >> 1) & 3);
    size_t src = (size_t)row * (D_ * 2) + (size_t)kt * 64 + ch * 16;
    async16((char*)bA + idx * 16, gA + src);
    async16((char*)bB + idx * 16, gB + src);
  }
}
__device__ __forceinline__ void comp_g(const unsigned short* bA,
    const unsigned short* bB, f32x16 (&acc)[2][2], int wr, int wc, int fr32, int hi1) {
#pragma unroll
  for (int ks = 0; ks < 2; ks++) {              // two K=16 steps in BK=32
    short8v a[2], bv[2];
#pragma unroll
    for (int m = 0; m < 2; m++) {
      int row = wr * 64 + m * 32 + fr32;
      int ch = (ks * 2 + hi1) ^ ((row >> 1) & 3);
      a[m] = *(const short8v*)&bA[row * 32 + ch * 8];
    }
#pragma unroll
    for (int n = 0; n < 2; n++) {
      int row = wc * 64 + n * 32 + fr32;
      int ch = (ks * 2 + hi1) ^ ((row >> 1) & 3);
      bv[n] = *(const short8v*)&bB[row * 32 + ch * 8];
    }
#pragma unroll
    for (int m = 0; m < 2; m++)
#pragma unroll
      for (int n = 0; n < 2; n++)
        acc[m][n] = __builtin_amdgcn_mfma_f32_32x32x16_bf16(a[m], bv[n], acc[m][n], 0, 0, 0);
  }
}

__global__ __launch_bounds__(256) void gemm_aw(
    const unsigned short* __restrict__ A,   // [M][K] bf16 (sent)
    const unsigned short* __restrict__ Bt,  // [N][K] bf16 (W^T)
    unsigned short* __restrict__ C) {       // [M][N] bf16 (a)
  const int K = D_, N = D_;
  __shared__ unsigned short sA0[128 * 32], sA1[128 * 32];
  __shared__ unsigned short sB0[128 * 32], sB1[128 * 32];
  int t = threadIdx.x;
  int w = t >> 6, lane = t & 63;
  int wr = w >> 1, wc = w & 1;
  int fr32 = lane & 31, hi1 = lane >> 5;
  // XCD-chunked swizzle: each XCD (bid%8) owns 8 consecutive m-panels x all n
  int bid = blockIdx.x;
  int wg = ((bid & 7) << 6) | (bid >> 3);
  int n0 = (wg & 7) * 128, m0 = (wg >> 3) * 128;
  f32x16 acc[2][2];
#pragma unroll
  for (int m = 0; m < 2; m++)
#pragma unroll
    for (int n = 0; n < 2; n++)
#pragma unroll
      for (int r = 0; r < 16; r++) acc[m][n][r] = 0.f;

  const char* gA = (const char*)(A + (size_t)m0 * K);
  const char* gB = (const char*)(Bt + (size_t)n0 * K);

  // Counted-vmcnt 2-buffer pipeline. Each stage_g = 4 global_load_lds/wave.
  // vmcnt(4) = "the OTHER buffer's 4 loads retired; mine still in flight".
  stage_g(gA, gB, sA0, sB0, t, 0);
#pragma unroll 1
  for (int kt = 0; kt < 30; kt += 2) {
    stage_g(gA, gB, sA1, sB1, t, kt + 1);
    VMCNT4; BARRIER;                      // buf0 ready; buf1 in flight
    __builtin_amdgcn_sched_barrier(0);
    comp_g(sA0, sB0, acc, wr, wc, fr32, hi1);
    BARRIER;                              // all waves done reading buf0
    stage_g(gA, gB, sA0, sB0, t, kt + 2);
    VMCNT4; BARRIER;                      // buf1 ready; buf0 in flight
    __builtin_amdgcn_sched_barrier(0);
    comp_g(sA1, sB1, acc, wr, wc, fr32, hi1);
    BARRIER;                              // all waves done reading buf1
  }
  // peeled tail: kt = 30
  stage_g(gA, gB, sA1, sB1, t, 31);
  VMCNT4; BARRIER;
  __builtin_amdgcn_sched_barrier(0);
  comp_g(sA0, sB0, acc, wr, wc, fr32, hi1);
  VMCNT0; BARRIER;                        // final tile: full drain
  __builtin_amdgcn_sched_barrier(0);
  comp_g(sA1, sB1, acc, wr, wc, fr32, hi1);

  // 32x32 C/D layout: col = lane&31, row = (reg&3) + 8*(reg>>2) + 4*(lane>>5)
#pragma unroll
  for (int m = 0; m < 2; m++) {
#pragma unroll
    for (int n = 0; n < 2; n++) {
#pragma unroll
      for (int r = 0; r < 16; r++) {
        int crow = (r & 3) + 8 * (r >> 2) + 4 * hi1;
        int row = wr * 64 + m * 32 + crow;
        C[(size_t)(m0 + row) * N + n0 + wc * 64 + n * 32 + fr32] = f2bf(acc[m][n][r]);
      }
    }
  }
}

// ---------------------------------------------------------------------------
// attn: per (b, 32-row S-tile): num = a.event^T (BK=128, dbuf, 16-chunk
// XOR swizzle), 16x16x32 MFMA, waves split E in half; row-norm from A
// fragments; cosine, contract with evw, combine halves via LDS, add base.
// XCD-aligned: bid&7 == b>>2, so a-reads hit the L2 of the XCD that wrote
// them in gemm_aw.
// ---------------------------------------------------------------------------
__device__ __forceinline__ void stage_a(const char* gA, const char* gE,
    unsigned short* bA, unsigned short* bE, int t, int kt) {
  // rows are 256B (128 bf16) = 16 chunks of 16B; swizzle ch ^= row&15
#pragma unroll
  for (int i = 0; i < 2; i++) {
    int idx = i * 256 + t;
    int row = idx >> 4;
    int ch = (idx & 15) ^ (row & 15);
    async16((char*)bA + idx * 16, gA + (size_t)row * (D_ * 2) + (size_t)kt * 256 + ch * 16);
  }
#pragma unroll
  for (int i = 0; i < 4; i++) {
    int idx = i * 256 + t;
    int row = idx >> 4;
    int ch = (idx & 15) ^ (row & 15);
    async16((char*)bE + idx * 16, gE + (size_t)row * (D_ * 2) + (size_t)kt * 256 + ch * 16);
  }
}
__device__ __forceinline__ void comp_a(const unsigned short* bA,
    const unsigned short* bE, f32x4 (&acc)[2], float& rsq, int w, int fr, int hi) {
  int rowA = (w >> 1) * 16 + fr;
  int ch = w & 1;
#pragma unroll
  for (int ks = 0; ks < 4; ks++) {
    int ca = ((ks * 4 + hi) ^ (rowA & 15)) << 3;
    short8v af = *(const short8v*)&bA[rowA * 128 + ca];
    if (ch == 0) {
#pragma unroll
      for (int j = 0; j < 8; j++) { float xv = bf2f((unsigned short)af[j]); rsq += xv * xv; }
    }
#pragma unroll
    for (int n = 0; n < 2; n++) {
      int rowE = ch * 32 + n * 16 + fr;
      int ce = ((ks * 4 + hi) ^ (rowE & 15)) << 3;
      short8v bv = *(const short8v*)&bE[rowE * 128 + ce];
      acc[n] = __builtin_amdgcn_mfma_f32_16x16x32_bf16(af, bv, acc[n], 0, 0, 0);
    }
  }
}

__global__ __launch_bounds__(256) void attn_ep(
    const unsigned short* __restrict__ Abf,  // [B*S][D] bf16 (a)
    const unsigned short* __restrict__ Ebf,  // [B*E][D] bf16 (event)
    const int* __restrict__ idx_e,
    const float* __restrict__ ne, const float* __restrict__ evw,
    const float* __restrict__ base,
    float* __restrict__ out) {
  // XCD-aligned decode: xcd = bid&7 handles batches [xcd*4, xcd*4+4)
  int bid = blockIdx.x;
  int xcd = bid & 7, loc = bid >> 3;
  int b = xcd * 4 + (loc >> 3);
  int s0 = (loc & 7) * 32;
  __shared__ unsigned short sA0[32 * 128], sA1[32 * 128];
  __shared__ unsigned short sE0[64 * 128], sE1[64 * 128];
  __shared__ float sRne[E_], sEvw[E_][2], sRna[32], sP[2][32][2];
  __shared__ float sMapn;
  int t = threadIdx.x;
  int w = t >> 6, lane = t & 63;
  int fr = lane & 15, hi = lane >> 4;
  if (t < E_) {
    sRne[t] = 1.0f / ne[b * E_ + t];
    sEvw[t][0] = evw[(size_t)(b * E_ + t) * 2 + 0];
    sEvw[t][1] = evw[(size_t)(b * E_ + t) * 2 + 1];
    unsigned long long mball = __ballot(idx_e[b * E_ + t] > 0);
    if (t == 0) sMapn = 1.0f / (float)__popcll(mball);
  }
  f32x4 acc[2];
#pragma unroll
  for (int n = 0; n < 2; n++) acc[n] = f32x4{0.f, 0.f, 0.f, 0.f};
  float rsq = 0.f;

  const char* gA = (const char*)(Abf + ((size_t)b * S_ + s0) * D_);
  const char* gE = (const char*)(Ebf + (size_t)b * E_ * D_);

  stage_a(gA, gE, sA0, sE0, t, 0);
  __syncthreads();
#pragma unroll 1
  for (int kt = 0; kt < 8; kt += 2) {
    stage_a(gA, gE, sA1, sE1, t, kt + 1);
    comp_a(sA0, sE0, acc, rsq, w, fr, hi);
    __syncthreads();
    if (kt + 2 < 8) stage_a(gA, gE, sA0, sE0, t, kt + 2);
    comp_a(sA1, sE1, acc, rsq, w, fr, hi);
    __syncthreads();
  }
  // row-norm: even waves hold squares; lanes fr, fr+16, fr+32, fr+48 share row
  rsq += __shfl_xor(rsq, 16);
  rsq += __shfl_xor(rsq, 32);
  if ((w & 1) == 0 && lane < 16)
    sRna[(w >> 1) * 16 + lane] = 1.0f / fmaxf(sqrtf(rsq), 1e-8f);
  __syncthreads();

  int ch = w & 1;
#pragma unroll
  for (int r = 0; r < 4; r++) {
    int srl = (w >> 1) * 16 + hi * 4 + r;    // row within 32-row tile
    float rna = sRna[srl];
    float a0 = 0.f, a1 = 0.f;
#pragma unroll
    for (int n = 0; n < 2; n++) {
      int e = ch * 32 + n * 16 + fr;
      float lg = acc[n][r] * rna * sRne[e];
      a0 += lg * sEvw[e][0];
      a1 += lg * sEvw[e][1];
    }
#pragma unroll
    for (int off = 1; off < 16; off <<= 1) {
      a0 += __shfl_xor(a0, off);
      a1 += __shfl_xor(a1, off);
    }
    if (fr == 0) { sP[ch][srl][0] = a0; sP[ch][srl][1] = a1; }
  }
  __syncthreads();
  if (t < 64) {
    int row = t >> 1, c = t & 1;
    float v = sP[0][row][c] + sP[1][row][c];
    size_t sg = (size_t)b * S_ + s0 + row;
    out[sg * 2 + c] = base[sg * 2 + c] + sMapn * v;
  }
}

extern "C" void kernel_launch(void* const* d_in, const int* in_sizes, int n_in,
                              void* d_out, int out_size, void* d_ws, size_t ws_size,
                              hipStream_t stream) {
  const float* emb   = (const float*)d_in[0];
  const float* W     = (const float*)d_in[1];
  const float* lin_w = (const float*)d_in[2];
  const float* lin_b = (const float*)d_in[3];
  const int* idx_s   = (const int*)d_in[4];
  const int* idx_e   = (const int*)d_in[5];
  const int* pos     = (const int*)d_in[6];
  float* out = (float*)d_out;

  char* ws = (char*)d_ws;
  const size_t MB = 1024 * 1024;
  unsigned short* sentb = (unsigned short*)(ws);            // 16 MB  [M][D]
  unsigned short* abf   = (unsigned short*)(ws + 16 * MB);  // 16 MB  [M][D]
  unsigned short* evb   = (unsigned short*)(ws + 32 * MB);  // 4 MB   [B*E][D]
  unsigned short* Wt    = (unsigned short*)(ws + 36 * MB);  // 2 MB   [D][D]
  float* ne   = (float*)(ws + 38 * MB);                     // 2048
  float* evw  = ne + 2048;                                  // 4096
  float* base = evw + 4096;                                 // 16384

  prep_all<<<3584, 256, 0, stream>>>(
      emb, W, lin_w, lin_b, idx_s, idx_e, pos, sentb, evb, Wt, base, ne, evw);
  gemm_aw<<<512, 256, 0, stream>>>(sentb, Wt, abf);
  attn_ep<<<B_ * 8, 256, 0, stream>>>(abf, evb, idx_e, ne, evw, base, out);
}

// Round 17
// 44.180 us; speedup vs baseline: 1.0359x; 1.0359x over previous
//
#include <hip/hip_runtime.h>

#define B_ 32
#define L_ 512
#define D_ 1024
#define S_ 256
#define E_ 64
#define POS_ 17
#define LWS 2065   // 2*D + POS
#define M_ (B_*S_) // 8192

typedef __attribute__((ext_vector_type(8))) short short8v;
typedef __attribute__((ext_vector_type(4))) float f32x4;
typedef __attribute__((ext_vector_type(16))) float f32x16;
typedef __attribute__((ext_vector_type(4))) unsigned short us4;

__device__ __forceinline__ unsigned short f2bf(float x) {
  union { float f; unsigned u; } v; v.f = x;
  unsigned r = v.u + 0x7FFFu + ((v.u >> 16) & 1u);
  return (unsigned short)(r >> 16);
}
__device__ __forceinline__ float bf2f(unsigned short b) {
  union { unsigned u; float f; } v; v.u = ((unsigned)b) << 16;
  return v.f;
}
// async global->LDS, 16B per lane. LDS dest must be linear (base + lane*16).
__device__ __forceinline__ void async16(void* lds, const void* g) {
  __builtin_amdgcn_global_load_lds(
      (const __attribute__((address_space(1))) unsigned int*)(unsigned long long)g,
      (__attribute__((address_space(3))) unsigned int*)(unsigned int)(unsigned long long)lds,
      16, 0, 0);
}

#define VMCNT4 asm volatile("s_waitcnt vmcnt(4)" ::: "memory")
#define VMCNT0 asm volatile("s_waitcnt vmcnt(0)" ::: "memory")
#define BARRIER __builtin_amdgcn_s_barrier()

// ---------------------------------------------------------------------------
// prep_all: one kernel, three roles by blockIdx range. Gather phases are
// ONE WAVE PER ROW, barrier-free (in-wave shfl reductions only).
//   [0, 2048)     : sent rows, 4/block (XCD-aligned: bid&7 owns rows
//                   [xcd*1024, +1024) to match gemm's XCD m-panels)
//   [2048, 2560)  : event rows, 4/block
//   [2560, 3584)  : W[k][n] f32 -> Wt[n][k] bf16 (32x32 tiles)
// ---------------------------------------------------------------------------
__global__ __launch_bounds__(256) void prep_all(
    const float* __restrict__ emb, const float* __restrict__ W,
    const float* __restrict__ lin_w, const float* __restrict__ lin_b,
    const int* __restrict__ idx_s, const int* __restrict__ idx_e,
    const int* __restrict__ pos_tag,
    unsigned short* __restrict__ sentb, unsigned short* __restrict__ evb,
    unsigned short* __restrict__ Wt,
    float* __restrict__ base, float* __restrict__ ne, float* __restrict__ evw) {
  int bid = blockIdx.x;
  int t = threadIdx.x;

  if (bid >= 2560) {  // ---- W transpose ----
    __shared__ float tile[32][33];
    int tt = bid - 2560;
    int bx = tt & 31, by = tt >> 5;
    int tx = t & 31, ty = t >> 5;  // 32 x 8
#pragma unroll
    for (int i = 0; i < 4; i++)
      tile[ty + i * 8][tx] = W[(size_t)(by * 32 + ty + i * 8) * D_ + bx * 32 + tx];
    __syncthreads();
#pragma unroll
    for (int i = 0; i < 4; i++)
      Wt[(size_t)(bx * 32 + ty + i * 8) * D_ + by * 32 + tx] = f2bf(tile[tx][ty + i * 8]);
    return;
  }

  int lane = t & 63, w = t >> 6;
  bool is_sent = bid < 2048;
  // sent: XCD-aligned bijection row = xcd*1024 + (bid>>3)*4 + w
  int row = is_sent ? (((bid & 7) << 10) | ((bid >> 3) << 2) | w)
                    : (((bid - 2048) << 2) | w);
  int b = is_sent ? (row >> 8) : (row >> 6);
  int idx = is_sent ? idx_s[row] : idx_e[row];
  float msk = idx > 0 ? 1.0f : 0.0f;
  const float* src = emb + ((size_t)b * L_ + (idx > 0 ? idx : 0)) * D_;

  float r0 = 0.f, r1 = 0.f, sq = 0.f;
  const float* lw0 = is_sent ? lin_w : (lin_w + D_);
  const float* lw1 = is_sent ? (lin_w + LWS) : (lin_w + LWS + D_);
  unsigned short* dst = is_sent ? (sentb + (size_t)row * D_)
                                : (evb + (size_t)row * D_);
#pragma unroll
  for (int j = 0; j < 4; j++) {
    int d = j * 256 + lane * 4;
    float4 v = *(const float4*)(src + d);
    v.x *= msk; v.y *= msk; v.z *= msk; v.w *= msk;
    us4 o; o.x = f2bf(v.x); o.y = f2bf(v.y); o.z = f2bf(v.z); o.w = f2bf(v.w);
    *(us4*)&dst[d] = o;
    float4 c0 = *(const float4*)(lw0 + d);              // 16B-aligned
    float4 c1 = *(const float4*)(lw1 + d);              // 4B-aligned (legal)
    r0 += v.x * c0.x + v.y * c0.y + v.z * c0.z + v.w * c0.w;
    r1 += v.x * c1.x + v.y * c1.y + v.z * c1.z + v.w * c1.w;
    if (!is_sent) sq += v.x * v.x + v.y * v.y + v.z * v.z + v.w * v.w;
  }
#pragma unroll
  for (int off = 32; off; off >>= 1) {
    r0 += __shfl_xor(r0, off);
    r1 += __shfl_xor(r1, off);
  }
  if (is_sent) {
    if (lane == 0) {
      int p = pos_tag[row]; if (p < 0) p = POS_ - 1;
      base[(size_t)row * 2 + 0] = r0 + lin_b[0] + lin_w[2 * D_ + p];
      base[(size_t)row * 2 + 1] = r1 + lin_b[1] + lin_w[LWS + 2 * D_ + p];
    }
  } else {
#pragma unroll
    for (int off = 32; off; off >>= 1) sq += __shfl_xor(sq, off);
    if (lane == 0) {
      ne[row] = fmaxf(sqrtf(sq), 1e-8f);
      evw[(size_t)row * 2 + 0] = r0;
      evw[(size_t)row * 2 + 1] = r1;
    }
  }
}

// ---------------------------------------------------------------------------
// gemm: a = sent @ W. 128x128 tile, BK=64, double-buffered LDS,
// counted-vmcnt pipeline — SAME sync skeleton as the best-measured config —
// but 512 threads / 8 waves (each wave owns 32x64 output, acc[2]):
// 64 KB LDS -> 2 blocks/CU -> 16 waves/CU = 4 waves/SIMD (was 2). R13-class
// counters (MfmaUtil 16%, HBM 8%, Occ 19%) said latency-bound; this doubles
// the scheduler's latency-hiding pool at constant LDS and lower VGPR.
// 32x32x16 MFMA, XOR-swizzled LDS via pre-swizzled global source,
// XCD-chunked block swizzle (XCD x owns m-rows [x*1024, x*1024+1024)).
// NOTE (R9 lesson): never read MFMA operands directly from global inside
// this loop — direct vmem reads share the vmcnt queue with global_load_lds
// and their waits drain the async pipeline (MfmaUtil 37%->13%, measured).
// ---------------------------------------------------------------------------
__device__ __forceinline__ void stage_g(const char* gA, const char* gB,
    unsigned short* bA, unsigned short* bB, int t, int kt) {
  int sc = ((t & 7) ^ ((t >> 3) & 7)) << 4;   // swizzled 16B-chunk in 128B row
#pragma unroll
  for (int i = 0; i < 2; i++) {               // 512 thr: 64 rows/pass
    int row = i * 64 + (t >> 3);
    size_t src = (size_t)row * (D_ * 2) + (size_t)kt * 128 + sc;
    async16((char*)bA + i * 8192 + t * 16, gA + src);
    async16((char*)bB + i * 8192 + t * 16, gB + src);
  }
}
__device__ __forceinline__ void comp_g(const unsigned short* bA,
    const unsigned short* bB, f32x16 (&acc)[2], int wr, int wc, int fr32, int hi1) {
  int x = fr32 & 7;
#pragma unroll
  for (int ks = 0; ks < 4; ks++) {              // four K=16 steps in BK=64
    int co = ((ks * 2 + hi1) ^ x) << 3;         // swizzled element offset
    short8v a, bv[2];
    a = *(const short8v*)&bA[(wr * 32 + fr32) * 64 + co];
#pragma unroll
    for (int n = 0; n < 2; n++)
      bv[n] = *(const short8v*)&bB[(wc * 64 + n * 32 + fr32) * 64 + co];
#pragma unroll
    for (int n = 0; n < 2; n++)
      acc[n] = __builtin_amdgcn_mfma_f32_32x32x16_bf16(a, bv[n], acc[n], 0, 0, 0);
  }
}

__global__ __launch_bounds__(512) void gemm_aw(
    const unsigned short* __restrict__ A,   // [M][K] bf16 (sent)
    const unsigned short* __restrict__ Bt,  // [N][K] bf16 (W^T)
    unsigned short* __restrict__ C) {       // [M][N] bf16 (a)
  const int K = D_, N = D_;
  __shared__ unsigned short sA0[128 * 64], sA1[128 * 64];
  __shared__ unsigned short sB0[128 * 64], sB1[128 * 64];
  int t = threadIdx.x;
  int w = t >> 6, lane = t & 63;      // 8 waves
  int wr = w >> 1, wc = w & 1;        // 4m x 2n; wave = 32 rows x 64 cols
  int fr32 = lane & 31, hi1 = lane >> 5;
  // XCD-chunked swizzle: each XCD (bid%8) owns 8 consecutive m-panels x all n
  int bid = blockIdx.x;
  int wg = ((bid & 7) << 6) | (bid >> 3);
  int n0 = (wg & 7) * 128, m0 = (wg >> 3) * 128;
  f32x16 acc[2];
#pragma unroll
  for (int n = 0; n < 2; n++)
#pragma unroll
    for (int r = 0; r < 16; r++) acc[n][r] = 0.f;

  const char* gA = (const char*)(A + (size_t)m0 * K);
  const char* gB = (const char*)(Bt + (size_t)n0 * K);

  // Counted-vmcnt 2-buffer pipeline. Each stage_g = 4 global_load_lds/wave.
  // vmcnt(4) = "the OTHER buffer's 4 loads retired; mine still in flight".
  stage_g(gA, gB, sA0, sB0, t, 0);
#pragma unroll 1
  for (int kt = 0; kt < 14; kt += 2) {
    stage_g(gA, gB, sA1, sB1, t, kt + 1);
    VMCNT4; BARRIER;                      // buf0 ready; buf1 in flight
    __builtin_amdgcn_sched_barrier(0);
    comp_g(sA0, sB0, acc, wr, wc, fr32, hi1);
    BARRIER;                              // all waves done reading buf0
    stage_g(gA, gB, sA0, sB0, t, kt + 2);
    VMCNT4; BARRIER;                      // buf1 ready; buf0 in flight
    __builtin_amdgcn_sched_barrier(0);
    comp_g(sA1, sB1, acc, wr, wc, fr32, hi1);
    BARRIER;                              // all waves done reading buf1
  }
  // peeled tail: kt = 14
  stage_g(gA, gB, sA1, sB1, t, 15);
  VMCNT4; BARRIER;
  __builtin_amdgcn_sched_barrier(0);
  comp_g(sA0, sB0, acc, wr, wc, fr32, hi1);
  VMCNT0; BARRIER;                        // final tile: full drain
  __builtin_amdgcn_sched_barrier(0);
  comp_g(sA1, sB1, acc, wr, wc, fr32, hi1);

  // 32x32 C/D layout: col = lane&31, row = (reg&3) + 8*(reg>>2) + 4*(lane>>5)
#pragma unroll
  for (int n = 0; n < 2; n++) {
#pragma unroll
    for (int r = 0; r < 16; r++) {
      int crow = (r & 3) + 8 * (r >> 2) + 4 * hi1;
      int row = wr * 32 + crow;
      C[(size_t)(m0 + row) * N + n0 + wc * 64 + n * 32 + fr32] = f2bf(acc[n][r]);
    }
  }
}

// ---------------------------------------------------------------------------
// attn: per (b, 32-row S-tile): num = a.event^T (BK=128, dbuf, 16-chunk
// XOR swizzle), 16x16x32 MFMA, waves split E in half; row-norm from A
// fragments; cosine, contract with evw, combine halves via LDS, add base.
// XCD-aligned: bid&7 == b>>2, so a-reads hit the L2 of the XCD that wrote
// them in gemm_aw.
// ---------------------------------------------------------------------------
__device__ __forceinline__ void stage_a(const char* gA, const char* gE,
    unsigned short* bA, unsigned short* bE, int t, int kt) {
  // rows are 256B (128 bf16) = 16 chunks of 16B; swizzle ch ^= row&15
#pragma unroll
  for (int i = 0; i < 2; i++) {
    int idx = i * 256 + t;
    int row = idx >> 4;
    int ch = (idx & 15) ^ (row & 15);
    async16((char*)bA + idx * 16, gA + (size_t)row * (D_ * 2) + (size_t)kt * 256 + ch * 16);
  }
#pragma unroll
  for (int i = 0; i < 4; i++) {
    int idx = i * 256 + t;
    int row = idx >> 4;
    int ch = (idx & 15) ^ (row & 15);
    async16((char*)bE + idx * 16, gE + (size_t)row * (D_ * 2) + (size_t)kt * 256 + ch * 16);
  }
}
__device__ __forceinline__ void comp_a(const unsigned short* bA,
    const unsigned short* bE, f32x4 (&acc)[2], float& rsq, int w, int fr, int hi) {
  int rowA = (w >> 1) * 16 + fr;
  int ch = w & 1;
#pragma unroll
  for (int ks = 0; ks < 4; ks++) {
    int ca = ((ks * 4 + hi) ^ (rowA & 15)) << 3;
    short8v af = *(const short8v*)&bA[rowA * 128 + ca];
    if (ch == 0) {
#pragma unroll
      for (int j = 0; j < 8; j++) { float xv = bf2f((unsigned short)af[j]); rsq += xv * xv; }
    }
#pragma unroll
    for (int n = 0; n < 2; n++) {
      int rowE = ch * 32 + n * 16 + fr;
      int ce = ((ks * 4 + hi) ^ (rowE & 15)) << 3;
      short8v bv = *(const short8v*)&bE[rowE * 128 + ce];
      acc[n] = __builtin_amdgcn_mfma_f32_16x16x32_bf16(af, bv, acc[n], 0, 0, 0);
    }
  }
}

__global__ __launch_bounds__(256) void attn_ep(
    const unsigned short* __restrict__ Abf,  // [B*S][D] bf16 (a)
    const unsigned short* __restrict__ Ebf,  // [B*E][D] bf16 (event)
    const int* __restrict__ idx_e,
    const float* __restrict__ ne, const float* __restrict__ evw,
    const float* __restrict__ base,
    float* __restrict__ out) {
  // XCD-aligned decode: xcd = bid&7 handles batches [xcd*4, xcd*4+4)
  int bid = blockIdx.x;
  int xcd = bid & 7, loc = bid >> 3;
  int b = xcd * 4 + (loc >> 3);
  int s0 = (loc & 7) * 32;
  __shared__ unsigned short sA0[32 * 128], sA1[32 * 128];
  __shared__ unsigned short sE0[64 * 128], sE1[64 * 128];
  __shared__ float sRne[E_], sEvw[E_][2], sRna[32], sP[2][32][2];
  __shared__ float sMapn;
  int t = threadIdx.x;
  int w = t >> 6, lane = t & 63;
  int fr = lane & 15, hi = lane >> 4;
  if (t < E_) {
    sRne[t] = 1.0f / ne[b * E_ + t];
    sEvw[t][0] = evw[(size_t)(b * E_ + t) * 2 + 0];
    sEvw[t][1] = evw[(size_t)(b * E_ + t) * 2 + 1];
    unsigned long long mball = __ballot(idx_e[b * E_ + t] > 0);
    if (t == 0) sMapn = 1.0f / (float)__popcll(mball);
  }
  f32x4 acc[2];
#pragma unroll
  for (int n = 0; n < 2; n++) acc[n] = f32x4{0.f, 0.f, 0.f, 0.f};
  float rsq = 0.f;

  const char* gA = (const char*)(Abf + ((size_t)b * S_ + s0) * D_);
  const char* gE = (const char*)(Ebf + (size_t)b * E_ * D_);

  stage_a(gA, gE, sA0, sE0, t, 0);
  __syncthreads();
#pragma unroll 1
  for (int kt = 0; kt < 8; kt += 2) {
    stage_a(gA, gE, sA1, sE1, t, kt + 1);
    comp_a(sA0, sE0, acc, rsq, w, fr, hi);
    __syncthreads();
    if (kt + 2 < 8) stage_a(gA, gE, sA0, sE0, t, kt + 2);
    comp_a(sA1, sE1, acc, rsq, w, fr, hi);
    __syncthreads();
  }
  // row-norm: even waves hold squares; lanes fr, fr+16, fr+32, fr+48 share row
  rsq += __shfl_xor(rsq, 16);
  rsq += __shfl_xor(rsq, 32);
  if ((w & 1) == 0 && lane < 16)
    sRna[(w >> 1) * 16 + lane] = 1.0f / fmaxf(sqrtf(rsq), 1e-8f);
  __syncthreads();

  int ch = w & 1;
#pragma unroll
  for (int r = 0; r < 4; r++) {
    int srl = (w >> 1) * 16 + hi * 4 + r;    // row within 32-row tile
    float rna = sRna[srl];
    float a0 = 0.f, a1 = 0.f;
#pragma unroll
    for (int n = 0; n < 2; n++) {
      int e = ch * 32 + n * 16 + fr;
      float lg = acc[n][r] * rna * sRne[e];
      a0 += lg * sEvw[e][0];
      a1 += lg * sEvw[e][1];
    }
#pragma unroll
    for (int off = 1; off < 16; off <<= 1) {
      a0 += __shfl_xor(a0, off);
      a1 += __shfl_xor(a1, off);
    }
    if (fr == 0) { sP[ch][srl][0] = a0; sP[ch][srl][1] = a1; }
  }
  __syncthreads();
  if (t < 64) {
    int row = t >> 1, c = t & 1;
    float v = sP[0][row][c] + sP[1][row][c];
    size_t sg = (size_t)b * S_ + s0 + row;
    out[sg * 2 + c] = base[sg * 2 + c] + sMapn * v;
  }
}

extern "C" void kernel_launch(void* const* d_in, const int* in_sizes, int n_in,
                              void* d_out, int out_size, void* d_ws, size_t ws_size,
                              hipStream_t stream) {
  const float* emb   = (const float*)d_in[0];
  const float* W     = (const float*)d_in[1];
  const float* lin_w = (const float*)d_in[2];
  const float* lin_b = (const float*)d_in[3];
  const int* idx_s   = (const int*)d_in[4];
  const int* idx_e   = (const int*)d_in[5];
  const int* pos     = (const int*)d_in[6];
  float* out = (float*)d_out;

  char* ws = (char*)d_ws;
  const size_t MB = 1024 * 1024;
  unsigned short* sentb = (unsigned short*)(ws);            // 16 MB  [M][D]
  unsigned short* abf   = (unsigned short*)(ws + 16 * MB);  // 16 MB  [M][D]
  unsigned short* evb   = (unsigned short*)(ws + 32 * MB);  // 4 MB   [B*E][D]
  unsigned short* Wt    = (unsigned short*)(ws + 36 * MB);  // 2 MB   [D][D]
  float* ne   = (float*)(ws + 38 * MB);                     // 2048
  float* evw  = ne + 2048;                                  // 4096
  float* base = evw + 4096;                                 // 16384

  prep_all<<<3584, 256, 0, stream>>>(
      emb, W, lin_w, lin_b, idx_s, idx_e, pos, sentb, evb, Wt, base, ne, evw);
  gemm_aw<<<512, 512, 0, stream>>>(sentb, Wt, abf);
  attn_ep<<<B_ * 8, 256, 0, stream>>>(abf, evb, idx_e, ne, evw, base, out);
}

// Round 18
// 43.229 us; speedup vs baseline: 1.0587x; 1.0220x over previous
//
#include <hip/hip_runtime.h>

#define B_ 32
#define L_ 512
#define D_ 1024
#define S_ 256
#define E_ 64
#define POS_ 17
#define LWS 2065   // 2*D + POS
#define M_ (B_*S_) // 8192

typedef __attribute__((ext_vector_type(8))) short short8v;
typedef __attribute__((ext_vector_type(4))) float f32x4;
typedef __attribute__((ext_vector_type(16))) float f32x16;
typedef __attribute__((ext_vector_type(4))) unsigned short us4;

__device__ __forceinline__ unsigned short f2bf(float x) {
  union { float f; unsigned u; } v; v.f = x;
  unsigned r = v.u + 0x7FFFu + ((v.u >> 16) & 1u);
  return (unsigned short)(r >> 16);
}
__device__ __forceinline__ float bf2f(unsigned short b) {
  union { unsigned u; float f; } v; v.u = ((unsigned)b) << 16;
  return v.f;
}
// async global->LDS, 16B per lane. LDS dest must be linear (base + lane*16).
__device__ __forceinline__ void async16(void* lds, const void* g) {
  __builtin_amdgcn_global_load_lds(
      (const __attribute__((address_space(1))) unsigned int*)(unsigned long long)g,
      (__attribute__((address_space(3))) unsigned int*)(unsigned int)(unsigned long long)lds,
      16, 0, 0);
}

#define VMCNT8 asm volatile("s_waitcnt vmcnt(8)" ::: "memory")
#define VMCNT0 asm volatile("s_waitcnt vmcnt(0)" ::: "memory")
#define BARRIER __builtin_amdgcn_s_barrier()

// ---------------------------------------------------------------------------
// FINAL CONFIGURATION (best measured: 43.26 us; reproduced 43.40 / 43.52).
// Decomposition: prep_all (gather+fold, ~5-9 us) -> gemm_aw (a = sent@W,
// ~34 us, ~500 TF at this N=1024 shape) -> attn_ep (cosine+contract, ~4 us).
// The gemm sits on a structural plateau: 9 measured variants within
// 43.3-45.8 us (schedule depth, geometry, occupancy, setprio, fusion);
// counters rule out HBM (8%), L2-BW, MFMA-pipe (16%), bank conflicts (~8%)
// — residual is the barrier-locked 16-K-tile short pipeline, whose proven
// escape (8-phase 256^2) cannot fill 256 CUs at M x N = 8192 x 1024.
// ---------------------------------------------------------------------------

// ---------------------------------------------------------------------------
// prep_all: one kernel, three roles by blockIdx range. Gather phases are
// ONE WAVE PER ROW, barrier-free (in-wave shfl reductions only).
//   [0, 2048)     : sent rows, 4/block (XCD-aligned: bid&7 owns rows
//                   [xcd*1024, +1024) to match gemm's XCD m-panels)
//   [2048, 2560)  : event rows, 4/block
//   [2560, 3584)  : W[k][n] f32 -> Wt[n][k] bf16 (32x32 tiles)
// ---------------------------------------------------------------------------
__global__ __launch_bounds__(256) void prep_all(
    const float* __restrict__ emb, const float* __restrict__ W,
    const float* __restrict__ lin_w, const float* __restrict__ lin_b,
    const int* __restrict__ idx_s, const int* __restrict__ idx_e,
    const int* __restrict__ pos_tag,
    unsigned short* __restrict__ sentb, unsigned short* __restrict__ evb,
    unsigned short* __restrict__ Wt,
    float* __restrict__ base, float* __restrict__ ne, float* __restrict__ evw) {
  int bid = blockIdx.x;
  int t = threadIdx.x;

  if (bid >= 2560) {  // ---- W transpose ----
    __shared__ float tile[32][33];
    int tt = bid - 2560;
    int bx = tt & 31, by = tt >> 5;
    int tx = t & 31, ty = t >> 5;  // 32 x 8
#pragma unroll
    for (int i = 0; i < 4; i++)
      tile[ty + i * 8][tx] = W[(size_t)(by * 32 + ty + i * 8) * D_ + bx * 32 + tx];
    __syncthreads();
#pragma unroll
    for (int i = 0; i < 4; i++)
      Wt[(size_t)(bx * 32 + ty + i * 8) * D_ + by * 32 + tx] = f2bf(tile[tx][ty + i * 8]);
    return;
  }

  int lane = t & 63, w = t >> 6;
  bool is_sent = bid < 2048;
  // sent: XCD-aligned bijection row = xcd*1024 + (bid>>3)*4 + w
  int row = is_sent ? (((bid & 7) << 10) | ((bid >> 3) << 2) | w)
                    : (((bid - 2048) << 2) | w);
  int b = is_sent ? (row >> 8) : (row >> 6);
  int idx = is_sent ? idx_s[row] : idx_e[row];
  float msk = idx > 0 ? 1.0f : 0.0f;
  const float* src = emb + ((size_t)b * L_ + (idx > 0 ? idx : 0)) * D_;

  float r0 = 0.f, r1 = 0.f, sq = 0.f;
  const float* lw0 = is_sent ? lin_w : (lin_w + D_);
  const float* lw1 = is_sent ? (lin_w + LWS) : (lin_w + LWS + D_);
  unsigned short* dst = is_sent ? (sentb + (size_t)row * D_)
                                : (evb + (size_t)row * D_);
#pragma unroll
  for (int j = 0; j < 4; j++) {
    int d = j * 256 + lane * 4;
    float4 v = *(const float4*)(src + d);
    v.x *= msk; v.y *= msk; v.z *= msk; v.w *= msk;
    us4 o; o.x = f2bf(v.x); o.y = f2bf(v.y); o.z = f2bf(v.z); o.w = f2bf(v.w);
    *(us4*)&dst[d] = o;
    float4 c0 = *(const float4*)(lw0 + d);              // 16B-aligned
    float4 c1 = *(const float4*)(lw1 + d);              // 4B-aligned (legal)
    r0 += v.x * c0.x + v.y * c0.y + v.z * c0.z + v.w * c0.w;
    r1 += v.x * c1.x + v.y * c1.y + v.z * c1.z + v.w * c1.w;
    if (!is_sent) sq += v.x * v.x + v.y * v.y + v.z * v.z + v.w * v.w;
  }
#pragma unroll
  for (int off = 32; off; off >>= 1) {
    r0 += __shfl_xor(r0, off);
    r1 += __shfl_xor(r1, off);
  }
  if (is_sent) {
    if (lane == 0) {
      int p = pos_tag[row]; if (p < 0) p = POS_ - 1;
      base[(size_t)row * 2 + 0] = r0 + lin_b[0] + lin_w[2 * D_ + p];
      base[(size_t)row * 2 + 1] = r1 + lin_b[1] + lin_w[LWS + 2 * D_ + p];
    }
  } else {
#pragma unroll
    for (int off = 32; off; off >>= 1) sq += __shfl_xor(sq, off);
    if (lane == 0) {
      ne[row] = fmaxf(sqrtf(sq), 1e-8f);
      evw[(size_t)row * 2 + 0] = r0;
      evw[(size_t)row * 2 + 1] = r1;
    }
  }
}

// ---------------------------------------------------------------------------
// gemm: a = sent @ W. 128x128 tile, BK=64, double-buffered LDS,
// counted-vmcnt pipeline: loads stay in flight across compute phases;
// 32x32x16 MFMA, XOR-swizzled LDS via pre-swizzled global source,
// XCD-chunked block swizzle (XCD x owns m-rows [x*1024, x*1024+1024)).
// NOTE (R9 lesson): never read MFMA operands directly from global inside
// this loop — direct vmem reads share the vmcnt queue with global_load_lds
// and their waits drain the async pipeline (MfmaUtil 37%->13%, measured).
// ---------------------------------------------------------------------------
__device__ __forceinline__ void stage_g(const char* gA, const char* gB,
    unsigned short* bA, unsigned short* bB, int t, int kt) {
  int sc = ((t & 7) ^ ((t >> 3) & 7)) << 4;   // swizzled 16B-chunk in 128B row
#pragma unroll
  for (int i = 0; i < 4; i++) {
    int row = i * 32 + (t >> 3);
    size_t src = (size_t)row * (D_ * 2) + (size_t)kt * 128 + sc;
    async16((char*)bA + i * 4096 + t * 16, gA + src);
    async16((char*)bB + i * 4096 + t * 16, gB + src);
  }
}
__device__ __forceinline__ void comp_g(const unsigned short* bA,
    const unsigned short* bB, f32x16 (&acc)[2][2], int wr, int wc, int fr32, int hi1) {
  int x = fr32 & 7;
#pragma unroll
  for (int ks = 0; ks < 4; ks++) {              // four K=16 steps in BK=64
    int co = ((ks * 2 + hi1) ^ x) << 3;         // swizzled element offset
    short8v a[2], bv[2];
#pragma unroll
    for (int m = 0; m < 2; m++)
      a[m] = *(const short8v*)&bA[(wr * 64 + m * 32 + fr32) * 64 + co];
#pragma unroll
    for (int n = 0; n < 2; n++)
      bv[n] = *(const short8v*)&bB[(wc * 64 + n * 32 + fr32) * 64 + co];
#pragma unroll
    for (int m = 0; m < 2; m++)
#pragma unroll
      for (int n = 0; n < 2; n++)
        acc[m][n] = __builtin_amdgcn_mfma_f32_32x32x16_bf16(a[m], bv[n], acc[m][n], 0, 0, 0);
  }
}

__global__ __launch_bounds__(256) void gemm_aw(
    const unsigned short* __restrict__ A,   // [M][K] bf16 (sent)
    const unsigned short* __restrict__ Bt,  // [N][K] bf16 (W^T)
    unsigned short* __restrict__ C) {       // [M][N] bf16 (a)
  const int K = D_, N = D_;
  __shared__ unsigned short sA0[128 * 64], sA1[128 * 64];
  __shared__ unsigned short sB0[128 * 64], sB1[128 * 64];
  int t = threadIdx.x;
  int w = t >> 6, lane = t & 63;
  int wr = w >> 1, wc = w & 1;
  int fr32 = lane & 31, hi1 = lane >> 5;
  // XCD-chunked swizzle: each XCD (bid%8) owns 8 consecutive m-panels x all n
  int bid = blockIdx.x;
  int wg = ((bid & 7) << 6) | (bid >> 3);
  int n0 = (wg & 7) * 128, m0 = (wg >> 3) * 128;
  f32x16 acc[2][2];
#pragma unroll
  for (int m = 0; m < 2; m++)
#pragma unroll
    for (int n = 0; n < 2; n++)
#pragma unroll
      for (int r = 0; r < 16; r++) acc[m][n][r] = 0.f;

  const char* gA = (const char*)(A + (size_t)m0 * K);
  const char* gB = (const char*)(Bt + (size_t)n0 * K);

  // Counted-vmcnt 2-buffer pipeline. Each stage_g = 8 global_load_lds/wave.
  // vmcnt(8) = "the OTHER buffer's 8 loads retired; mine still in flight".
  stage_g(gA, gB, sA0, sB0, t, 0);
#pragma unroll 1
  for (int kt = 0; kt < 14; kt += 2) {
    stage_g(gA, gB, sA1, sB1, t, kt + 1);
    VMCNT8; BARRIER;                      // buf0 ready; buf1 in flight
    __builtin_amdgcn_sched_barrier(0);
    comp_g(sA0, sB0, acc, wr, wc, fr32, hi1);
    BARRIER;                              // all waves done reading buf0
    stage_g(gA, gB, sA0, sB0, t, kt + 2);
    VMCNT8; BARRIER;                      // buf1 ready; buf0 in flight
    __builtin_amdgcn_sched_barrier(0);
    comp_g(sA1, sB1, acc, wr, wc, fr32, hi1);
    BARRIER;                              // all waves done reading buf1
  }
  // peeled tail: kt = 14
  stage_g(gA, gB, sA1, sB1, t, 15);
  VMCNT8; BARRIER;
  __builtin_amdgcn_sched_barrier(0);
  comp_g(sA0, sB0, acc, wr, wc, fr32, hi1);
  VMCNT0; BARRIER;                        // final tile: full drain
  __builtin_amdgcn_sched_barrier(0);
  comp_g(sA1, sB1, acc, wr, wc, fr32, hi1);

  // 32x32 C/D layout: col = lane&31, row = (reg&3) + 8*(reg>>2) + 4*(lane>>5)
#pragma unroll
  for (int m = 0; m < 2; m++) {
#pragma unroll
    for (int n = 0; n < 2; n++) {
#pragma unroll
      for (int r = 0; r < 16; r++) {
        int crow = (r & 3) + 8 * (r >> 2) + 4 * hi1;
        int row = wr * 64 + m * 32 + crow;
        C[(size_t)(m0 + row) * N + n0 + wc * 64 + n * 32 + fr32] = f2bf(acc[m][n][r]);
      }
    }
  }
}

// ---------------------------------------------------------------------------
// attn: per (b, 32-row S-tile): num = a.event^T (BK=128, dbuf, 16-chunk
// XOR swizzle), 16x16x32 MFMA, waves split E in half; row-norm from A
// fragments; cosine, contract with evw, combine halves via LDS, add base.
// XCD-aligned: bid&7 == b>>2, so a-reads hit the L2 of the XCD that wrote
// them in gemm_aw.
// ---------------------------------------------------------------------------
__device__ __forceinline__ void stage_a(const char* gA, const char* gE,
    unsigned short* bA, unsigned short* bE, int t, int kt) {
  // rows are 256B (128 bf16) = 16 chunks of 16B; swizzle ch ^= row&15
#pragma unroll
  for (int i = 0; i < 2; i++) {
    int idx = i * 256 + t;
    int row = idx >> 4;
    int ch = (idx & 15) ^ (row & 15);
    async16((char*)bA + idx * 16, gA + (size_t)row * (D_ * 2) + (size_t)kt * 256 + ch * 16);
  }
#pragma unroll
  for (int i = 0; i < 4; i++) {
    int idx = i * 256 + t;
    int row = idx >> 4;
    int ch = (idx & 15) ^ (row & 15);
    async16((char*)bE + idx * 16, gE + (size_t)row * (D_ * 2) + (size_t)kt * 256 + ch * 16);
  }
}
__device__ __forceinline__ void comp_a(const unsigned short* bA,
    const unsigned short* bE, f32x4 (&acc)[2], float& rsq, int w, int fr, int hi) {
  int rowA = (w >> 1) * 16 + fr;
  int ch = w & 1;
#pragma unroll
  for (int ks = 0; ks < 4; ks++) {
    int ca = ((ks * 4 + hi) ^ (rowA & 15)) << 3;
    short8v af = *(const short8v*)&bA[rowA * 128 + ca];
    if (ch == 0) {
#pragma unroll
      for (int j = 0; j < 8; j++) { float xv = bf2f((unsigned short)af[j]); rsq += xv * xv; }
    }
#pragma unroll
    for (int n = 0; n < 2; n++) {
      int rowE = ch * 32 + n * 16 + fr;
      int ce = ((ks * 4 + hi) ^ (rowE & 15)) << 3;
      short8v bv = *(const short8v*)&bE[rowE * 128 + ce];
      acc[n] = __builtin_amdgcn_mfma_f32_16x16x32_bf16(af, bv, acc[n], 0, 0, 0);
    }
  }
}

__global__ __launch_bounds__(256) void attn_ep(
    const unsigned short* __restrict__ Abf,  // [B*S][D] bf16 (a)
    const unsigned short* __restrict__ Ebf,  // [B*E][D] bf16 (event)
    const int* __restrict__ idx_e,
    const float* __restrict__ ne, const float* __restrict__ evw,
    const float* __restrict__ base,
    float* __restrict__ out) {
  // XCD-aligned decode: xcd = bid&7 handles batches [xcd*4, xcd*4+4)
  int bid = blockIdx.x;
  int xcd = bid & 7, loc = bid >> 3;
  int b = xcd * 4 + (loc >> 3);
  int s0 = (loc & 7) * 32;
  __shared__ unsigned short sA0[32 * 128], sA1[32 * 128];
  __shared__ unsigned short sE0[64 * 128], sE1[64 * 128];
  __shared__ float sRne[E_], sEvw[E_][2], sRna[32], sP[2][32][2];
  __shared__ float sMapn;
  int t = threadIdx.x;
  int w = t >> 6, lane = t & 63;
  int fr = lane & 15, hi = lane >> 4;
  if (t < E_) {
    sRne[t] = 1.0f / ne[b * E_ + t];
    sEvw[t][0] = evw[(size_t)(b * E_ + t) * 2 + 0];
    sEvw[t][1] = evw[(size_t)(b * E_ + t) * 2 + 1];
    unsigned long long mball = __ballot(idx_e[b * E_ + t] > 0);
    if (t == 0) sMapn = 1.0f / (float)__popcll(mball);
  }
  f32x4 acc[2];
#pragma unroll
  for (int n = 0; n < 2; n++) acc[n] = f32x4{0.f, 0.f, 0.f, 0.f};
  float rsq = 0.f;

  const char* gA = (const char*)(Abf + ((size_t)b * S_ + s0) * D_);
  const char* gE = (const char*)(Ebf + (size_t)b * E_ * D_);

  stage_a(gA, gE, sA0, sE0, t, 0);
  __syncthreads();
#pragma unroll 1
  for (int kt = 0; kt < 8; kt += 2) {
    stage_a(gA, gE, sA1, sE1, t, kt + 1);
    comp_a(sA0, sE0, acc, rsq, w, fr, hi);
    __syncthreads();
    if (kt + 2 < 8) stage_a(gA, gE, sA0, sE0, t, kt + 2);
    comp_a(sA1, sE1, acc, rsq, w, fr, hi);
    __syncthreads();
  }
  // row-norm: even waves hold squares; lanes fr, fr+16, fr+32, fr+48 share row
  rsq += __shfl_xor(rsq, 16);
  rsq += __shfl_xor(rsq, 32);
  if ((w & 1) == 0 && lane < 16)
    sRna[(w >> 1) * 16 + lane] = 1.0f / fmaxf(sqrtf(rsq), 1e-8f);
  __syncthreads();

  int ch = w & 1;
#pragma unroll
  for (int r = 0; r < 4; r++) {
    int srl = (w >> 1) * 16 + hi * 4 + r;    // row within 32-row tile
    float rna = sRna[srl];
    float a0 = 0.f, a1 = 0.f;
#pragma unroll
    for (int n = 0; n < 2; n++) {
      int e = ch * 32 + n * 16 + fr;
      float lg = acc[n][r] * rna * sRne[e];
      a0 += lg * sEvw[e][0];
      a1 += lg * sEvw[e][1];
    }
#pragma unroll
    for (int off = 1; off < 16; off <<= 1) {
      a0 += __shfl_xor(a0, off);
      a1 += __shfl_xor(a1, off);
    }
    if (fr == 0) { sP[ch][srl][0] = a0; sP[ch][srl][1] = a1; }
  }
  __syncthreads();
  if (t < 64) {
    int row = t >> 1, c = t & 1;
    float v = sP[0][row][c] + sP[1][row][c];
    size_t sg = (size_t)b * S_ + s0 + row;
    out[sg * 2 + c] = base[sg * 2 + c] + sMapn * v;
  }
}

extern "C" void kernel_launch(void* const* d_in, const int* in_sizes, int n_in,
                              void* d_out, int out_size, void* d_ws, size_t ws_size,
                              hipStream_t stream) {
  const float* emb   = (const float*)d_in[0];
  const float* W     = (const float*)d_in[1];
  const float* lin_w = (const float*)d_in[2];
  const float* lin_b = (const float*)d_in[3];
  const int* idx_s   = (const int*)d_in[4];
  const int* idx_e   = (const int*)d_in[5];
  const int* pos     = (const int*)d_in[6];
  float* out = (float*)d_out;

  char* ws = (char*)d_ws;
  const size_t MB = 1024 * 1024;
  unsigned short* sentb = (unsigned short*)(ws);            // 16 MB  [M][D]
  unsigned short* abf   = (unsigned short*)(ws + 16 * MB);  // 16 MB  [M][D]
  unsigned short* evb   = (unsigned short*)(ws + 32 * MB);  // 4 MB   [B*E][D]
  unsigned short* Wt    = (unsigned short*)(ws + 36 * MB);  // 2 MB   [D][D]
  float* ne   = (float*)(ws + 38 * MB);                     // 2048
  float* evw  = ne + 2048;                                  // 4096
  float* base = evw + 4096;                                 // 16384

  prep_all<<<3584, 256, 0, stream>>>(
      emb, W, lin_w, lin_b, idx_s, idx_e, pos, sentb, evb, Wt, base, ne, evw);
  gemm_aw<<<512, 256, 0, stream>>>(sentb, Wt, abf);
  attn_ep<<<B_ * 8, 256, 0, stream>>>(abf, evb, idx_e, ne, evw, base, out);
}